// Round 1
// baseline (1262.608 us; speedup 1.0000x reference)
//
#include <hip/hip_runtime.h>

// Neighbor search: M=N=12288, DIM=3.
// d_out layout (float32, flat, return order):
//   [0 .. M]                      row_splits (M+1 ints as floats)
//   [M+1 .. M+1+M*N)              mask (0.0 / 1.0)
//   [M+1+M*N .. M+1+2*M*N)        weights (d2 if mask else 0)
//
// Bit-exactness: replicate numpy/BLAS fp32 arithmetic:
//   sq = (x0*x0 + x1*x1) + x2*x2          (each op rounded)
//   dot = fma(q2,d2, fma(q1,d1, q0*d0))   (sgemm ascending-k FMA chain)
//   d2  = (sq_q + sq_d) - 2*dot ; max(d2,0) ; mask = d2 <= r*r
// All via explicit __f*_rn intrinsics to forbid re-contraction.

__global__ __launch_bounds__(256) void nbr_kernel(
    const float* __restrict__ data,
    const float* __restrict__ queries,
    const float* __restrict__ radius_p,
    float* __restrict__ out,
    int* __restrict__ counts,
    int N, long long mask_off, long long w_off)
{
    const int m = blockIdx.x;
    const int tid = threadIdx.x;

    const float r = radius_p[0];
    const float r2 = __fmul_rn(r, r);
    const float q0 = queries[3 * m + 0];
    const float q1 = queries[3 * m + 1];
    const float q2 = queries[3 * m + 2];
    const float sq_q = __fadd_rn(
        __fadd_rn(__fmul_rn(q0, q0), __fmul_rn(q1, q1)), __fmul_rn(q2, q2));

    float* mask_row = out + mask_off + (long long)m * N;
    float* w_row    = out + w_off    + (long long)m * N;

    int cnt = 0;

    auto compute = [&](int n, float& mv, float& wv) -> int {
        const float d0 = data[3 * n + 0];
        const float d1 = data[3 * n + 1];
        const float d2e = data[3 * n + 2];
        const float sq_d = __fadd_rn(
            __fadd_rn(__fmul_rn(d0, d0), __fmul_rn(d1, d1)), __fmul_rn(d2e, d2e));
        const float dot = __fmaf_rn(q2, d2e, __fmaf_rn(q1, d1, __fmul_rn(q0, d0)));
        const float s = __fadd_rn(sq_q, sq_d);
        float v = __fsub_rn(s, __fmul_rn(2.0f, dot));
        v = fmaxf(v, 0.0f);
        const bool in = (v <= r2);
        mv = in ? 1.0f : 0.0f;
        wv = in ? v : 0.0f;
        return in ? 1 : 0;
    };

    // Row base (flat) is == 1 (mod 4) elements: peel head n=0,1,2 and tail n=N-1
    // so the body runs on 16B-aligned float4 chunks.
    if (tid < 3) {
        float mv, wv;
        cnt += compute(tid, mv, wv);
        mask_row[tid] = mv;
        w_row[tid] = wv;
    } else if (tid == 3) {
        float mv, wv;
        cnt += compute(N - 1, mv, wv);
        mask_row[N - 1] = mv;
        w_row[N - 1] = wv;
    }

    const int nchunks = (N - 4) >> 2;  // 3071 for N=12288
    for (int j = tid; j < nchunks; j += 256) {
        const int n = 3 + 4 * j;
        float4 mv4, wv4;
        cnt += compute(n + 0, mv4.x, wv4.x);
        cnt += compute(n + 1, mv4.y, wv4.y);
        cnt += compute(n + 2, mv4.z, wv4.z);
        cnt += compute(n + 3, mv4.w, wv4.w);
        *reinterpret_cast<float4*>(mask_row + n) = mv4;  // 16B-aligned
        *reinterpret_cast<float4*>(w_row + n) = wv4;     // 16B-aligned
    }

    // Block count reduction: wave shuffle, then LDS across the 4 waves.
    for (int off = 32; off > 0; off >>= 1) cnt += __shfl_down(cnt, off);
    __shared__ int lds_cnt;
    if (tid == 0) lds_cnt = 0;
    __syncthreads();
    if ((tid & 63) == 0) atomicAdd(&lds_cnt, cnt);
    __syncthreads();
    if (tid == 0) counts[m] = lds_cnt;
}

// Single-block exclusive scan of counts[M] -> row_splits[M+1] (as floats).
__global__ __launch_bounds__(256) void scan_kernel(
    const int* __restrict__ counts, float* __restrict__ out, int M)
{
    __shared__ int sums[256];
    const int t = threadIdx.x;
    const int CH = (M + 255) / 256;  // 48 for M=12288
    const int base = t * CH;

    int local[64];  // CH <= 64 assumed
    int s = 0;
    for (int i = 0; i < CH; ++i) {
        const int v = (base + i < M) ? counts[base + i] : 0;
        local[i] = v;
        s += v;
    }
    sums[t] = s;
    __syncthreads();
    for (int off = 1; off < 256; off <<= 1) {
        const int v = (t >= off) ? sums[t - off] : 0;
        __syncthreads();
        sums[t] += v;
        __syncthreads();
    }
    int prefix = sums[t] - s;  // exclusive prefix of this thread's chunk
    for (int i = 0; i < CH; ++i) {
        if (base + i < M) out[base + i] = (float)prefix;
        prefix += local[i];
    }
    if (t == 255) out[M] = (float)prefix;  // total
}

extern "C" void kernel_launch(void* const* d_in, const int* in_sizes, int n_in,
                              void* d_out, int out_size, void* d_ws, size_t ws_size,
                              hipStream_t stream) {
    const float* data    = (const float*)d_in[0];
    const float* queries = (const float*)d_in[1];
    const float* radius  = (const float*)d_in[2];

    const int N = in_sizes[0] / 3;  // 12288
    const int M = in_sizes[1] / 3;  // 12288

    float* out = (float*)d_out;
    int* counts = (int*)d_ws;

    const long long mask_off = (long long)M + 1;
    const long long w_off = mask_off + (long long)M * N;

    nbr_kernel<<<M, 256, 0, stream>>>(data, queries, radius, out, counts,
                                      N, mask_off, w_off);
    scan_kernel<<<1, 256, 0, stream>>>(counts, out, M);
}

// Round 2
// 1239.469 us; speedup vs baseline: 1.0187x; 1.0187x over previous
//
#include <hip/hip_runtime.h>

// Neighbor search: M=N=12288, DIM=3.
// d_out layout (float32, flat, return order):
//   [0 .. M]                row_splits (M+1 counts-prefix as floats)
//   [M+1 .. M+1+M*N)        mask (0.0 / 1.0)
//   [M+1+M*N .. +2*M*N)     weights (d2 if mask else 0)
//
// R1 analysis: scalar 12B-stride data gathers made one wave-load span 48
// cache lines -> L1-request bound (~485us vs ~195us store floor). Fix:
// stage data tiles in LDS (coalesced float4), read word-stride-3 from LDS
// (2 lanes/bank = conflict-free), per-element thread mapping with scalar
// dword stores (256B/wave, fully coalesced).
//
// Bit-exactness vs numpy/BLAS fp32:
//   sq = (x0*x0 + x1*x1) + x2*x2          (each op rounded)
//   dot = fma(q2,d2, fma(q1,d1, q0*d0))   (sgemm ascending-k FMA chain)
//   d2  = (sq_q + sq_d) - 2*dot ; max(d2,0) ; mask = d2 <= r*r
// All via explicit __f*_rn intrinsics to forbid re-contraction.

#define TILE 2048  // points per LDS tile: 2048*3*4 = 24 KB -> 6 blocks/CU

__global__ __launch_bounds__(256) void nbr_kernel(
    const float* __restrict__ data,
    const float* __restrict__ queries,
    const float* __restrict__ radius_p,
    float* __restrict__ out,
    int* __restrict__ counts,
    int N, long long mask_off, long long w_off)
{
    __shared__ float tile[TILE * 3];

    const int m = blockIdx.x;
    const int tid = threadIdx.x;

    const float r = radius_p[0];
    const float r2 = __fmul_rn(r, r);
    const float q0 = queries[3 * m + 0];
    const float q1 = queries[3 * m + 1];
    const float q2 = queries[3 * m + 2];
    const float sq_q = __fadd_rn(
        __fadd_rn(__fmul_rn(q0, q0), __fmul_rn(q1, q1)), __fmul_rn(q2, q2));

    float* mask_row = out + mask_off + (long long)m * N;
    float* w_row    = out + w_off    + (long long)m * N;

    int cnt = 0;

    auto compute = [&](float d0, float d1, float d2e, float& mv, float& wv) -> int {
        const float sq_d = __fadd_rn(
            __fadd_rn(__fmul_rn(d0, d0), __fmul_rn(d1, d1)), __fmul_rn(d2e, d2e));
        const float dot = __fmaf_rn(q2, d2e, __fmaf_rn(q1, d1, __fmul_rn(q0, d0)));
        const float s = __fadd_rn(sq_q, sq_d);
        float v = __fsub_rn(s, __fmul_rn(2.0f, dot));
        v = fmaxf(v, 0.0f);
        const bool in = (v <= r2);
        mv = in ? 1.0f : 0.0f;
        wv = in ? v : 0.0f;
        return in ? 1 : 0;
    };

    for (int tb = 0; tb < N; tb += TILE) {
        const int lim = min(TILE, N - tb);

        __syncthreads();  // previous tile's readers done before overwrite
        if (lim == TILE) {
            // Coalesced float4 staging: 1536 float4s / 256 threads = 6 each.
            const float4* src = reinterpret_cast<const float4*>(data + 3LL * tb);
            float4* dst = reinterpret_cast<float4*>(tile);
            #pragma unroll
            for (int w = 0; w < TILE * 3 / 4 / 256; ++w)
                dst[w * 256 + tid] = src[w * 256 + tid];
        } else {
            for (int w = tid; w < lim * 3; w += 256)
                tile[w] = data[3LL * tb + w];
        }
        __syncthreads();

        if (lim == TILE) {
            #pragma unroll
            for (int k = 0; k < TILE / 256; ++k) {
                const int e = k * 256 + tid;
                const float d0  = tile[3 * e + 0];  // word-stride-3: 2 lanes/bank, free
                const float d1  = tile[3 * e + 1];
                const float d2e = tile[3 * e + 2];
                float mv, wv;
                cnt += compute(d0, d1, d2e, mv, wv);
                mask_row[tb + e] = mv;  // lanes contiguous: 256B/wave coalesced
                w_row[tb + e] = wv;
            }
        } else {
            for (int e = tid; e < lim; e += 256) {
                const float d0  = tile[3 * e + 0];
                const float d1  = tile[3 * e + 1];
                const float d2e = tile[3 * e + 2];
                float mv, wv;
                cnt += compute(d0, d1, d2e, mv, wv);
                mask_row[tb + e] = mv;
                w_row[tb + e] = wv;
            }
        }
    }

    // Block count reduction: wave shuffle, then LDS across the 4 waves.
    for (int off = 32; off > 0; off >>= 1) cnt += __shfl_down(cnt, off);
    __shared__ int lds_cnt;
    if (tid == 0) lds_cnt = 0;
    __syncthreads();
    if ((tid & 63) == 0) atomicAdd(&lds_cnt, cnt);
    __syncthreads();
    if (tid == 0) counts[m] = lds_cnt;
}

// Single-block exclusive scan of counts[M] -> row_splits[M+1] (as floats).
__global__ __launch_bounds__(256) void scan_kernel(
    const int* __restrict__ counts, float* __restrict__ out, int M)
{
    __shared__ int sums[256];
    const int t = threadIdx.x;
    const int CH = (M + 255) / 256;  // 48 for M=12288
    const int base = t * CH;

    int local[64];  // CH <= 64 assumed
    int s = 0;
    for (int i = 0; i < CH; ++i) {
        const int v = (base + i < M) ? counts[base + i] : 0;
        local[i] = v;
        s += v;
    }
    sums[t] = s;
    __syncthreads();
    for (int off = 1; off < 256; off <<= 1) {
        const int v = (t >= off) ? sums[t - off] : 0;
        __syncthreads();
        sums[t] += v;
        __syncthreads();
    }
    int prefix = sums[t] - s;  // exclusive prefix of this thread's chunk
    for (int i = 0; i < CH; ++i) {
        if (base + i < M) out[base + i] = (float)prefix;
        prefix += local[i];
    }
    if (t == 255) out[M] = (float)prefix;  // total
}

extern "C" void kernel_launch(void* const* d_in, const int* in_sizes, int n_in,
                              void* d_out, int out_size, void* d_ws, size_t ws_size,
                              hipStream_t stream) {
    const float* data    = (const float*)d_in[0];
    const float* queries = (const float*)d_in[1];
    const float* radius  = (const float*)d_in[2];

    const int N = in_sizes[0] / 3;  // 12288
    const int M = in_sizes[1] / 3;  // 12288

    float* out = (float*)d_out;
    int* counts = (int*)d_ws;

    const long long mask_off = (long long)M + 1;
    const long long w_off = mask_off + (long long)M * N;

    nbr_kernel<<<M, 256, 0, stream>>>(data, queries, radius, out, counts,
                                      N, mask_off, w_off);
    scan_kernel<<<1, 256, 0, stream>>>(counts, out, M);
}